// Round 4
// baseline (106.877 us; speedup 1.0000x reference)
//
#include <hip/hip_runtime.h>

#define HW 28
#define NPIX 784
#define NB 512
#define PADW2 34                 // row stride in PIXELS (cols -3..30); 136 B, 8B-aligned rows
#define PADH 34                  // rows -3..30
#define IMG_U (PADH * PADW2)     // 1156 packed pixels = 4624 B per branch buffer

// ---------------------------------------------------------------------------
// r20 structure: TWO WAVES PER BRANCH split by column parity. Each lane does
// a 7x1 output tile (half of r19's 7x2): 686 dot2 per conv. Same aligned
// uint2 tap reads; parity selects tp[t+P] at COMPILE TIME (template), so the
// two waves run disjoint code paths with zero divergence.
// Rationale: VALUBusy pinned ~53% across 3 inner-loop variants -> idle is
// occupancy (512x512 grid = half of 256CUx2048 capacity, 4 lockstep
// waves/SIMD whose stalls coincide). 1024-thread blocks -> 8 waves/SIMD.
// Weights stay wave-uniform in SGPRs (r19); den dot2 vs (ew,0) full rate.
// ---------------------------------------------------------------------------
template<int P>
__device__ __forceinline__ void conv1col(const unsigned* sbuf,
                                         unsigned wpack,  // lane i<49: packed (qw,ew)
                                         int R0, int c, float o[7])
{
    // issue row-0 tap loads FIRST; the 49 readlanes cover their latency
    const uint2* rq0 = (const uint2*)(sbuf + R0 * PADW2 + 2 * c);  // 8B-aligned
    uint2 p0 = rq0[0], p1 = rq0[1], p2 = rq0[2], p3 = rq0[3];

    unsigned Wq[49];
#pragma unroll
    for (int i = 0; i < 49; ++i)
        Wq[i] = __builtin_amdgcn_readlane(wpack, i);

    float num[7], den[7];
#pragma unroll
    for (int r = 0; r < 7; ++r) { num[r] = 0.f; den[r] = 0.f; }

#pragma unroll
    for (int rr = 0; rr < 13; ++rr) {
        // depth-1 row prefetch (r20: worth ~2us; keep)
        uint2 n0, n1, n2, n3;
        if (rr < 12) {
            const uint2* rq = (const uint2*)(sbuf + (R0 + rr + 1) * PADW2 + 2 * c);
            n0 = rq[0]; n1 = rq[1]; n2 = rq[2]; n3 = rq[3];
            __builtin_amdgcn_sched_barrier(0);   // pin: loads stay above compute
        }
        unsigned tp[8] = {p0.x, p0.y, p1.x, p1.y, p2.x, p2.y, p3.x, p3.y};
#pragma unroll
        for (int r = 0; r < 7; ++r) {
            if (r > rr || rr - r > 6) continue;     // compile-time fold
            const int di = rr - r;
#pragma unroll
            for (int t = 0; t < 7; ++t) {
                unsigned wq = Wq[di * 7 + t];
                unsigned wd;
                asm("s_lshr_b32 %0, %1, 16" : "=s"(wd) : "s"(wq));  // (ew, 0)
                asm("v_dot2_f32_f16 %0, %1, %2, %0"
                    : "+v"(num[r]) : "v"(tp[t + P]), "s"(wq));
                asm("v_dot2_f32_f16 %0, %1, %2, %0"
                    : "+v"(den[r]) : "v"(tp[t + P]), "s"(wd));
            }
        }
        if (rr < 12) { p0 = n0; p1 = n1; p2 = n2; p3 = n3; }
    }
#pragma unroll
    for (int r = 0; r < 7; ++r)
        o[r] = num[r] * __builtin_amdgcn_rcpf(den[r]);
}

__device__ __forceinline__ float sigmoidf_(float s) {
    return __builtin_amdgcn_rcpf(1.f + __expf(-s));
}

// ---------------------------------------------------------------------------
// FULLY FUSED, 16 waves/block, TWO WAVES PER BRANCH, one block per image.
// LDS ~38.6 KB -> 2 blocks/CU (79 KB) = 32 waves/CU = 100% wave capacity.
// __launch_bounds__(1024,2) -> VGPR cap 64 (live set ~45, must not spill).
// Buffer phases now need block barriers (two waves share a branch buffer).
// ---------------------------------------------------------------------------
__global__ __launch_bounds__(1024, 2) void smorph_net_kernel(
    const float* __restrict__ x,       // [512,784]
    const float* __restrict__ sw,      // [8,2,49]
    const float* __restrict__ sa,      // [8,2]
    const float* __restrict__ W1, const float* __restrict__ b1,
    const float* __restrict__ W2, const float* __restrict__ b2,
    const float* __restrict__ W3, const float* __restrict__ b3,
    float* __restrict__ out)           // [512,10]
{
    __shared__ __align__(16) unsigned bufs[8][IMG_U];      // 36,992 B
    __shared__ __align__(16) float    mlp[392 + 120 + 128]; // 2,560 B (feat|h1|h2)

    const int b    = blockIdx.x;       // 512 blocks
    const int tid  = threadIdx.x;      // 0..1023
    const int f    = tid >> 7;         // branch = pair of waves
    const int t128 = tid & 127;        // 0..127 within branch
    const int lane = tid & 63;
    const int P    = (t128 >> 6);      // 0 = even cols, 1 = odd cols

    unsigned* buf = bufs[f];
    const float* src = x + (size_t)b * NPIX;

    const float a1 = sa[f * 2 + 0];
    const float a2 = sa[f * 2 + 1];

    // per-branch packed weights: lane i<49 holds (qw=w*ew, ew) for its tap.
    // Both waves of the branch compute identical values (register-private).
    unsigned wp1 = 0, wp2 = 0;
    if (lane < 49) {
        union { _Float16 h[2]; unsigned u; } p;
        float w1v = sw[(f * 2 + 0) * 49 + lane];
        float e1  = __expf(a1 * w1v);
        p.h[0] = (_Float16)(w1v * e1);          // lo = qw
        p.h[1] = (_Float16)e1;                  // hi = ew
        wp1 = p.u;
        float w2v = sw[(f * 2 + 1) * 49 + lane];
        float e2  = __expf(a2 * w2v);
        p.h[0] = (_Float16)(w2v * e2);
        p.h[1] = (_Float16)e2;
        wp2 = p.u;
    }

    // phase 0a: fill whole padded buffer with border constant (ev=1, pv=0)
    {
        uint4* b4 = (uint4*)buf;                 // 289 uint4 per branch
        const uint4 fv = make_uint4(0x00003C00u, 0x00003C00u, 0x00003C00u, 0x00003C00u);
#pragma unroll
        for (int k = 0; k < 3; ++k) {
            int i = t128 + 128 * k;
            if (i < IMG_U / 4) b4[i] = fv;
        }
    }
    __syncthreads();                             // fill before interior overwrite

    // phase 0b: interior — fully-unrolled INDEPENDENT loads (batched latency)
#pragma unroll
    for (int k = 0; k < 7; ++k) {
        int p = t128 + 128 * k;
        if (p < NPIX) {
            float v = src[p];
            int pi = p / HW;
            int pj = p - pi * HW;
            float e = __expf(a1 * v);
            union { _Float16 h[2]; unsigned u; } pk;
            pk.h[0] = (_Float16)e;
            pk.h[1] = (_Float16)(v * e);
            buf[(pi + 3) * PADW2 + (pj + 3)] = pk.u;
        }
    }
    __syncthreads();                             // pack done before conv1

    const bool act = (lane < 56);
    const int s  = lane / 14;          // strip (output rows 7s..7s+6)
    const int c  = lane - s * 14;      // column pair 0..13
    const int R0 = 7 * s;
    const int j  = 2 * c + P;          // this lane's output column

    float o[7];
    if (act) {
        if (P == 0) conv1col<0>(buf, wp1, R0, c, o);
        else        conv1col<1>(buf, wp1, R0, c, o);
    }
    __syncthreads();                             // conv1 reads done before s2 write

    // stage-2 packed (ev,pv) overwrite interior in place
    if (act) {
#pragma unroll
        for (int r = 0; r < 7; ++r) {
            union { _Float16 h[2]; unsigned u; } pk;
            float e0 = __expf(a2 * o[r]);
            pk.h[0] = (_Float16)e0; pk.h[1] = (_Float16)(o[r] * e0);
            buf[(R0 + r + 3) * PADW2 + (j + 3)] = pk.u;
        }
    }
    __syncthreads();                             // s2 written before conv2

    if (act) {
        if (P == 0) conv1col<0>(buf, wp2, R0, c, o);
        else        conv1col<1>(buf, wp2, R0, c, o);
    }
    __syncthreads();                             // conv2 reads done before plane write

    // dense 28x28 f32 plane aliased over own buf (3136 B <= 4624 B)
    float* outp = (float*)buf;
    if (act) {
#pragma unroll
        for (int r = 0; r < 7; ++r)
            outp[(R0 + r) * HW + j] = o[r];
    }
    __syncthreads();                             // plane complete before pool

    float* feat = mlp;
    float* h1   = mlp + 392;
    float* h2   = mlp + 512;

    // 4x4 mean pool: wave P=0 of each branch, lanes <49
    if (P == 0 && lane < 49) {
        int pi = lane / 7;
        int pj = lane - pi * 7;
        float poolsum = 0.f;
#pragma unroll
        for (int di = 0; di < 4; ++di)
#pragma unroll
            for (int dj = 0; dj < 4; ++dj)
                poolsum += outp[(pi * 4 + di) * HW + (pj * 4 + dj)];
        feat[f * 49 + lane] = poolsum * 0.0625f;
    }
    __syncthreads();

    // ---- inline MLP ----
    // layer 1: 8 lanes per neuron (120 neurons x 8 = 960 threads)
    if (tid < 960) {
        int n = tid >> 3, h = tid & 7;
        const float4* wr = (const float4*)(W1 + n * 392);
        const float4* fv = (const float4*)feat;
        float c0 = 0.f, c1 = 0.f, c2 = 0.f, c3 = 0.f;
        for (int k = h; k < 98; k += 8) {
            float4 w = wr[k];
            float4 v = fv[k];
            c0 = fmaf(w.x, v.x, c0);
            c1 = fmaf(w.y, v.y, c1);
            c2 = fmaf(w.z, v.z, c2);
            c3 = fmaf(w.w, v.w, c3);
        }
        float acc = (c0 + c1) + (c2 + c3);
        acc += __shfl_xor(acc, 1);
        acc += __shfl_xor(acc, 2);
        acc += __shfl_xor(acc, 4);
        if (h == 0) h1[n] = sigmoidf_(acc + b1[n]);
    }
    __syncthreads();

    if (tid < 336) {
        int n = tid >> 2, h = tid & 3;
        const float4* wr = (const float4*)(W2 + n * 120);
        const float4* hv = (const float4*)h1;
        float c0 = 0.f, c1 = 0.f, c2 = 0.f, c3 = 0.f;
        for (int k = h; k < 30; k += 4) {
            float4 w = wr[k];
            float4 v = hv[k];
            c0 = fmaf(w.x, v.x, c0);
            c1 = fmaf(w.y, v.y, c1);
            c2 = fmaf(w.z, v.z, c2);
            c3 = fmaf(w.w, v.w, c3);
        }
        float acc = (c0 + c1) + (c2 + c3);
        acc += __shfl_xor(acc, 1);
        acc += __shfl_xor(acc, 2);
        if (h == 0) h2[n] = sigmoidf_(acc + b2[n]);
    }
    __syncthreads();

    if (tid < 40) {
        int n = tid >> 2, q = tid & 3;
        const float4* wr = (const float4*)(W3 + n * 84);
        const float4* hv = (const float4*)h2;
        float c0 = 0.f, c1 = 0.f, c2 = 0.f, c3 = 0.f;
        for (int k = q; k < 21; k += 4) {
            float4 w = wr[k];
            float4 v = hv[k];
            c0 = fmaf(w.x, v.x, c0);
            c1 = fmaf(w.y, v.y, c1);
            c2 = fmaf(w.z, v.z, c2);
            c3 = fmaf(w.w, v.w, c3);
        }
        float acc = (c0 + c1) + (c2 + c3);
        acc += __shfl_xor(acc, 1);
        acc += __shfl_xor(acc, 2);
        if (q == 0) out[(size_t)b * 10 + n] = sigmoidf_(acc + b3[n]);
    }
}

extern "C" void kernel_launch(void* const* d_in, const int* in_sizes, int n_in,
                              void* d_out, int out_size, void* d_ws, size_t ws_size,
                              hipStream_t stream) {
    const float* x  = (const float*)d_in[0];
    const float* sw = (const float*)d_in[1];
    const float* sa = (const float*)d_in[2];
    const float* W1 = (const float*)d_in[3];
    const float* b1 = (const float*)d_in[4];
    const float* W2 = (const float*)d_in[5];
    const float* b2 = (const float*)d_in[6];
    const float* W3 = (const float*)d_in[7];
    const float* b3 = (const float*)d_in[8];
    float* out = (float*)d_out;

    smorph_net_kernel<<<NB, 1024, 0, stream>>>(x, sw, sa, W1, b1, W2, b2, W3, b3, out);
}

// Round 5
// 101.677 us; speedup vs baseline: 1.0511x; 1.0511x over previous
//
#include <hip/hip_runtime.h>

#define HW 28
#define NPIX 784
#define NB 512
#define PADW2 34                 // row stride in PIXELS (cols -3..30); 136 B, 8B-aligned rows
#define PADH 34                  // rows -3..30
#define IMG_U (PADH * PADW2)     // 1156 packed pixels = 4624 B per branch buffer

// ---------------------------------------------------------------------------
// r21: ROLLED conv — I$ experiment. Evidence r0..r4: VALUBusy pinned ~50%
// regardless of instruction mix; dot2 measured HALF-rate (4cyc), so r0==r2;
// prefetch bought only 2us; parity-split regressed. Surviving theory: the
// ~25KB fully-unrolled conv code + rest ~= 32KB == L1I capacity -> streaming
// fetch bound. This version rolls the conv over di (7 iters, unroll 1) with
// r-inner unrolled (accs statically indexed). Weight row per di from a
// padded LDS table [7][8] via 2 broadcast b128; wd = wq>>16 in-register.
// Conv code ~25KB -> ~2KB. Costs ~15% more issue (taps re-read per di).
// ---------------------------------------------------------------------------
__device__ __forceinline__ void conv2col(const unsigned* sbuf,
                                         const unsigned* wlds,  // [7][8] packed, 16B-aligned
                                         int R0, int c, float o0[7], float o1[7])
{
    float num0[7], num1[7], den0[7], den1[7];
#pragma unroll
    for (int r = 0; r < 7; ++r) {
        num0[r] = 0.f; num1[r] = 0.f; den0[r] = 0.f; den1[r] = 0.f;
    }

#pragma unroll 1                       // KEEP ROLLED: the whole point
    for (int di = 0; di < 7; ++di) {
        // weight row di: 8 packed words, 2 broadcast b128 (conflict-free)
        const uint4* wp = (const uint4*)(wlds + di * 8);
        uint4 wa = wp[0], wb = wp[1];
        unsigned wq[7] = {wa.x, wa.y, wa.z, wa.w, wb.x, wb.y, wb.z};
        unsigned wd[7];
#pragma unroll
        for (int t = 0; t < 7; ++t) wd[t] = wq[t] >> 16;   // (ew, 0)

        // first tap row of this di
        const uint2* rp = (const uint2*)(sbuf + (R0 + di) * PADW2 + 2 * c);
        uint2 a0 = rp[0], a1 = rp[1], a2 = rp[2], a3 = rp[3];

#pragma unroll
        for (int r = 0; r < 7; ++r) {
            // depth-1 prefetch of next r's tap row (regs rename via unroll)
            uint2 b0, b1, b2, b3;
            if (r < 6) {
                const uint2* rn = (const uint2*)(sbuf + (R0 + di + r + 1) * PADW2 + 2 * c);
                b0 = rn[0]; b1 = rn[1]; b2 = rn[2]; b3 = rn[3];
                __builtin_amdgcn_sched_barrier(0);   // pin loads above compute
            }
            unsigned tp[8] = {a0.x, a0.y, a1.x, a1.y, a2.x, a2.y, a3.x, a3.y};
#pragma unroll
            for (int t = 0; t < 7; ++t) {
                asm("v_dot2_f32_f16 %0, %1, %2, %0"
                    : "+v"(num0[r]) : "v"(tp[t]),     "v"(wq[t]));
                asm("v_dot2_f32_f16 %0, %1, %2, %0"
                    : "+v"(num1[r]) : "v"(tp[t + 1]), "v"(wq[t]));
                asm("v_dot2_f32_f16 %0, %1, %2, %0"
                    : "+v"(den0[r]) : "v"(tp[t]),     "v"(wd[t]));
                asm("v_dot2_f32_f16 %0, %1, %2, %0"
                    : "+v"(den1[r]) : "v"(tp[t + 1]), "v"(wd[t]));
            }
            if (r < 6) { a0 = b0; a1 = b1; a2 = b2; a3 = b3; }
        }
    }
#pragma unroll
    for (int r = 0; r < 7; ++r) {
        o0[r] = num0[r] * __builtin_amdgcn_rcpf(den0[r]);
        o1[r] = num1[r] * __builtin_amdgcn_rcpf(den1[r]);
    }
}

__device__ __forceinline__ float sigmoidf_(float s) {
    return __builtin_amdgcn_rcpf(1.f + __expf(-s));
}

// ---------------------------------------------------------------------------
// FULLY FUSED, 8 waves/block, ONE BRANCH PER WAVE, one block per image
// (r13/r17 structure). LDS ~42.1 KB -> 2 blocks/CU (84 KB <= 160 KB).
// __launch_bounds__(512,2): VGPR cap 128 (r12 lesson).
// ---------------------------------------------------------------------------
__global__ __launch_bounds__(512, 2) void smorph_net_kernel(
    const float* __restrict__ x,       // [512,784]
    const float* __restrict__ sw,      // [8,2,49]
    const float* __restrict__ sa,      // [8,2]
    const float* __restrict__ W1, const float* __restrict__ b1,
    const float* __restrict__ W2, const float* __restrict__ b2,
    const float* __restrict__ W3, const float* __restrict__ b3,
    float* __restrict__ out)           // [512,10]
{
    __shared__ __align__(16) unsigned bufs[8][IMG_U];       // 36,992 B
    __shared__ __align__(16) unsigned wtab[8][2][7][8];     //  3,584 B
    __shared__ __align__(16) float    mlp[392 + 120 + 128]; //  2,560 B

    const int b    = blockIdx.x;       // 512 blocks
    const int tid  = threadIdx.x;      // 0..511
    const int f    = tid >> 6;         // wave = branch
    const int lane = tid & 63;

    unsigned* buf = bufs[f];
    const float* src = x + (size_t)b * NPIX;

    const float a1 = sa[f * 2 + 0];
    const float a2 = sa[f * 2 + 1];

    // per-branch packed weight tables in LDS: [di][t], pad col 7 zeroed.
    // Wave-local writes, read later by same wave (LDS in-order per wave).
    if (lane < 49) {
        int di = lane / 7, t = lane - di * 7;
        union { _Float16 h[2]; unsigned u; } p;
        float w1v = sw[(f * 2 + 0) * 49 + lane];
        float e1  = __expf(a1 * w1v);
        p.h[0] = (_Float16)(w1v * e1);          // lo = qw
        p.h[1] = (_Float16)e1;                  // hi = ew
        wtab[f][0][di][t] = p.u;
        float w2v = sw[(f * 2 + 1) * 49 + lane];
        float e2  = __expf(a2 * w2v);
        p.h[0] = (_Float16)(w2v * e2);
        p.h[1] = (_Float16)e2;
        wtab[f][1][di][t] = p.u;
    } else if (lane < 56) {
        wtab[f][0][lane - 49][7] = 0u;           // zero pad column
        wtab[f][1][lane - 49][7] = 0u;
    }

    // phase 0a: fill whole padded buffer with border constant (ev=1, pv=0)
    for (int idx = lane; idx < IMG_U; idx += 64)
        buf[idx] = 0x00003C00u;

    // phase 0b: interior — 13 fully-unrolled INDEPENDENT loads per lane so
    // all global loads issue up front (one latency, not 19 chained)
#pragma unroll
    for (int k = 0; k < 13; ++k) {
        int p = lane + 64 * k;
        if (p < NPIX) {
            float v = src[p];
            int pi = p / HW;
            int pj = p - pi * HW;
            float e = __expf(a1 * v);
            union { _Float16 h[2]; unsigned u; } pk;
            pk.h[0] = (_Float16)e;
            pk.h[1] = (_Float16)(v * e);
            buf[(pi + 3) * PADW2 + (pj + 3)] = pk.u;
        }
    }

    const bool act = (lane < 56);
    const int s  = lane / 14;          // strip (output rows 7s..7s+6)
    const int c  = lane - s * 14;      // column pair 0..13
    const int R0 = 7 * s;
    const int j2 = 2 * c;

    float o0[7], o1[7];
    if (act) conv2col(buf, &wtab[f][0][0][0], R0, c, o0, o1);

    // stage-2 packed (ev,pv) overwrite interior in place (own-wave reads done)
    if (act) {
#pragma unroll
        for (int r = 0; r < 7; ++r) {
            union { _Float16 h[2]; unsigned u; } pk;
            float e0 = __expf(a2 * o0[r]);
            pk.h[0] = (_Float16)e0; pk.h[1] = (_Float16)(o0[r] * e0);
            buf[(R0 + r + 3) * PADW2 + (j2 + 3)] = pk.u;
            float e1 = __expf(a2 * o1[r]);
            pk.h[0] = (_Float16)e1; pk.h[1] = (_Float16)(o1[r] * e1);
            buf[(R0 + r + 3) * PADW2 + (j2 + 4)] = pk.u;
        }
    }

    if (act) conv2col(buf, &wtab[f][1][0][0], R0, c, o0, o1);

    // dense 28x28 f32 plane aliased over own buf (3136 B <= 4624 B)
    float* outp = (float*)buf;
    if (act) {
#pragma unroll
        for (int r = 0; r < 7; ++r) {
            outp[(R0 + r) * HW + j2]     = o0[r];
            outp[(R0 + r) * HW + j2 + 1] = o1[r];
        }
    }

    // 4x4 mean pool -> feat (separate LDS buffer, no aliasing hazard)
    float* feat = mlp;
    float* h1   = mlp + 392;
    float* h2   = mlp + 512;

    if (lane < 49) {
        int pi = lane / 7;
        int pj = lane - pi * 7;
        float poolsum = 0.f;
#pragma unroll
        for (int di = 0; di < 4; ++di)
#pragma unroll
            for (int dj = 0; dj < 4; ++dj)
                poolsum += outp[(pi * 4 + di) * HW + (pj * 4 + dj)];
        feat[f * 49 + lane] = poolsum * 0.0625f;
    }
    __syncthreads();

    // ---- inline MLP (4 lanes per neuron) ----
    if (tid < 480) {
        int n = tid >> 2, h = tid & 3;
        const float4* wr = (const float4*)(W1 + n * 392);
        const float4* fv = (const float4*)feat;
        float c0 = 0.f, c1 = 0.f, c2 = 0.f, c3 = 0.f;
        for (int k = h; k < 98; k += 4) {
            float4 w = wr[k];
            float4 v = fv[k];
            c0 = fmaf(w.x, v.x, c0);
            c1 = fmaf(w.y, v.y, c1);
            c2 = fmaf(w.z, v.z, c2);
            c3 = fmaf(w.w, v.w, c3);
        }
        float acc = (c0 + c1) + (c2 + c3);
        acc += __shfl_xor(acc, 1);
        acc += __shfl_xor(acc, 2);
        if (h == 0) h1[n] = sigmoidf_(acc + b1[n]);
    }
    __syncthreads();

    if (tid < 336) {
        int n = tid >> 2, h = tid & 3;
        const float4* wr = (const float4*)(W2 + n * 120);
        const float4* hv = (const float4*)h1;
        float c0 = 0.f, c1 = 0.f, c2 = 0.f, c3 = 0.f;
        for (int k = h; k < 30; k += 4) {
            float4 w = wr[k];
            float4 v = hv[k];
            c0 = fmaf(w.x, v.x, c0);
            c1 = fmaf(w.y, v.y, c1);
            c2 = fmaf(w.z, v.z, c2);
            c3 = fmaf(w.w, v.w, c3);
        }
        float acc = (c0 + c1) + (c2 + c3);
        acc += __shfl_xor(acc, 1);
        acc += __shfl_xor(acc, 2);
        if (h == 0) h2[n] = sigmoidf_(acc + b2[n]);
    }
    __syncthreads();

    if (tid < 40) {
        int n = tid >> 2, q = tid & 3;
        const float4* wr = (const float4*)(W3 + n * 84);
        const float4* hv = (const float4*)h2;
        float c0 = 0.f, c1 = 0.f, c2 = 0.f, c3 = 0.f;
        for (int k = q; k < 21; k += 4) {
            float4 w = wr[k];
            float4 v = hv[k];
            c0 = fmaf(w.x, v.x, c0);
            c1 = fmaf(w.y, v.y, c1);
            c2 = fmaf(w.z, v.z, c2);
            c3 = fmaf(w.w, v.w, c3);
        }
        float acc = (c0 + c1) + (c2 + c3);
        acc += __shfl_xor(acc, 1);
        acc += __shfl_xor(acc, 2);
        if (q == 0) out[(size_t)b * 10 + n] = sigmoidf_(acc + b3[n]);
    }
}

extern "C" void kernel_launch(void* const* d_in, const int* in_sizes, int n_in,
                              void* d_out, int out_size, void* d_ws, size_t ws_size,
                              hipStream_t stream) {
    const float* x  = (const float*)d_in[0];
    const float* sw = (const float*)d_in[1];
    const float* sa = (const float*)d_in[2];
    const float* W1 = (const float*)d_in[3];
    const float* b1 = (const float*)d_in[4];
    const float* W2 = (const float*)d_in[5];
    const float* b2 = (const float*)d_in[6];
    const float* W3 = (const float*)d_in[7];
    const float* b3 = (const float*)d_in[8];
    float* out = (float*)d_out;

    smorph_net_kernel<<<NB, 512, 0, stream>>>(x, sw, sa, W1, b1, W2, b2, W3, b3, out);
}